// Round 3
// baseline (736.502 us; speedup 1.0000x reference)
//
#include <hip/hip_runtime.h>
#include <hip/hip_bf16.h>

#define B_ 2048
#define D_ 512
#define N_ 100000
#define F_ 64
#define NEGV (-1000000.0f)

typedef __bf16 bfx8 __attribute__((ext_vector_type(8)));
typedef float f32x4 __attribute__((ext_vector_type(4)));
typedef unsigned short u16x8 __attribute__((ext_vector_type(8)));

static __device__ __forceinline__ unsigned short f2bf(float f) {
  unsigned u = __float_as_uint(f);
  unsigned r = (u + 0x7fffu + ((u >> 16) & 1u)) >> 16;
  return (unsigned short)r;
}
static __device__ __forceinline__ float bf2f(unsigned short u) {
  return __uint_as_float(((unsigned)u) << 16);
}

static __device__ __forceinline__ void async_copy16(const void* g, void* l) {
  __builtin_amdgcn_global_load_lds((const __attribute__((address_space(1))) void*)g,
                                   (__attribute__((address_space(3))) void*)l, 16, 0, 0);
}

// ---- targets (fp32, matches reference einsum) + out init -------------------
__global__ void targets_init(const float* __restrict__ q, const float* __restrict__ rhs,
                             const int* __restrict__ queries, float* __restrict__ targets,
                             float* __restrict__ out) {
  __shared__ float wsum[4];
  int b = blockIdx.x;
  int tid = threadIdx.x, lane = tid & 63, w = tid >> 6;
  int p = queries[b * 3 + 2];
  float s = 0.f;
  for (int d = tid; d < D_; d += 256) s += q[b * D_ + d] * rhs[(size_t)d * N_ + p];
  for (int off = 32; off; off >>= 1) s += __shfl_down(s, off, 64);
  if (lane == 0) wsum[w] = s;
  __syncthreads();
  if (tid == 0) {
    targets[b] = wsum[0] + wsum[1] + wsum[2] + wsum[3];
    out[b] = 1.0f;
  }
}

// ---- q fp32 -> bf16 --------------------------------------------------------
__global__ void convert_q(const float* __restrict__ q, unsigned short* __restrict__ qb) {
  int i = blockIdx.x * blockDim.x + threadIdx.x;  // over B*D/4
  const float4* q4 = (const float4*)q;
  float4 v = q4[i];
  ushort4 o;
  o.x = f2bf(v.x); o.y = f2bf(v.y); o.z = f2bf(v.z); o.w = f2bf(v.w);
  ((ushort4*)qb)[i] = o;
}

// ---- rhs (D x N fp32) -> rt (N x D bf16), 64x64 LDS tile transpose ---------
// read phase: float4 (16B/lane) except the single n-tail block (OOB-page risk)
__global__ void transpose_rhs(const float* __restrict__ rhs, unsigned short* __restrict__ rt) {
  __shared__ float tile[64][65];
  int n0 = blockIdx.x * 64, d0 = blockIdx.y * 64;
  int tid = threadIdx.x;
  if (n0 + 64 <= N_) {
#pragma unroll
    for (int p = 0; p < 4; ++p) {
      int e = p * 256 + tid;          // 1024 float4 chunks = 64 d x 16 n-chunks
      int d = e >> 4, c4 = e & 15;
      float4 v = *(const float4*)(rhs + (size_t)(d0 + d) * N_ + n0 + c4 * 4);
      tile[d][c4 * 4 + 0] = v.x; tile[d][c4 * 4 + 1] = v.y;
      tile[d][c4 * 4 + 2] = v.z; tile[d][c4 * 4 + 3] = v.w;
    }
  } else {
    int c = tid & 63, r4 = tid >> 6;
#pragma unroll
    for (int p = 0; p < 16; ++p) {
      int d = r4 + p * 4;
      if (n0 + c < N_) tile[d][c] = rhs[(size_t)(d0 + d) * N_ + n0 + c];
    }
  }
  __syncthreads();
#pragma unroll
  for (int p = 0; p < 4; ++p) {
    int e = p * 256 + tid;            // 1024 ushort4 slots = 64 n x 16 d-groups
    int n = e >> 4, dg = e & 15;
    if (n0 + n < N_) {
      ushort4 o;
      o.x = f2bf(tile[dg * 4 + 0][n]);
      o.y = f2bf(tile[dg * 4 + 1][n]);
      o.z = f2bf(tile[dg * 4 + 2][n]);
      o.w = f2bf(tile[dg * 4 + 3][n]);
      *(ushort4*)(rt + (size_t)(n0 + n) * D_ + d0 + dg * 4) = o;
    }
  }
}

// ---- main: bf16 MFMA GEMM (BK=64) -> per-row count of (score >= target) ----
__global__ void __launch_bounds__(256) gemm_count(
    const unsigned short* __restrict__ qb,   // B x D bf16
    const unsigned short* __restrict__ rt,   // N x D bf16 (transposed rhs)
    const float* __restrict__ targets,
    float* __restrict__ out) {
  __shared__ unsigned short As[128 * 64];   // [m][k], k=64 per tile
  __shared__ unsigned short Bs[128 * 64];   // [n][k]
  __shared__ float sT[128];
  __shared__ int cnt2[2][128];

  int tid = threadIdx.x;
  int m0 = blockIdx.x * 128;
  int n0 = blockIdx.y * 128;

  if (tid < 128) sT[tid] = targets[m0 + tid];

  int w = tid >> 6, lane = tid & 63;
  int mw = (w & 1) * 64, nw = (w >> 1) * 64;
  int quad = lane >> 4, l16 = lane & 15;

  f32x4 acc[4][4];
  f32x4 z = {0.f, 0.f, 0.f, 0.f};
#pragma unroll
  for (int i = 0; i < 4; ++i)
#pragma unroll
    for (int j = 0; j < 4; ++j) acc[i][j] = z;

  for (int kt = 0; kt < 8; ++kt) {
    int k0 = kt * 64;
    __syncthreads();
#pragma unroll
    for (int i = 0; i < 4; ++i) {
      int c = i * 256 + tid;            // 1024 chunks of 16B
      int m = c >> 3, jj = c & 7;
      const unsigned short* gp = qb + (size_t)(m0 + m) * D_ + k0 + jj * 8;
      async_copy16(gp, As + c * 8);
    }
#pragma unroll
    for (int i = 0; i < 4; ++i) {
      int c = i * 256 + tid;
      int n = c >> 3, jj = c & 7;
      int ng = n0 + n; if (ng > N_ - 1) ng = N_ - 1;   // clamp tail
      const unsigned short* gp = rt + (size_t)ng * D_ + k0 + jj * 8;
      async_copy16(gp, Bs + c * 8);
    }
    __syncthreads();

#pragma unroll
    for (int kh = 0; kh < 2; ++kh) {
      bfx8 a[4], b[4];
#pragma unroll
      for (int mi = 0; mi < 4; ++mi) {
        int m = mw + mi * 16 + l16;
        u16x8 au = *(const u16x8*)(As + m * 64 + kh * 32 + quad * 8);
        a[mi] = __builtin_bit_cast(bfx8, au);
      }
#pragma unroll
      for (int ni = 0; ni < 4; ++ni) {
        int n = nw + ni * 16 + l16;
        u16x8 bu = *(const u16x8*)(Bs + n * 64 + kh * 32 + quad * 8);
        b[ni] = __builtin_bit_cast(bfx8, bu);
      }
#pragma unroll
      for (int mi = 0; mi < 4; ++mi)
#pragma unroll
        for (int ni = 0; ni < 4; ++ni)
          acc[mi][ni] = __builtin_amdgcn_mfma_f32_16x16x32_bf16(a[mi], b[ni], acc[mi][ni], 0, 0, 0);
    }
  }

  // epilogue: compare vs target, quad shuffle-reduce, conflict-free stores
#pragma unroll
  for (int mi = 0; mi < 4; ++mi) {
#pragma unroll
    for (int reg = 0; reg < 4; ++reg) {
      int rl = mw + mi * 16 + quad * 4 + reg;   // C/D: row=(lane>>4)*4+reg
      float t = sT[rl];
      int c = 0;
#pragma unroll
      for (int ni = 0; ni < 4; ++ni) {
        int col = n0 + nw + ni * 16 + l16;      // C/D: col=lane&15
        if (col < N_ && acc[mi][ni][reg] >= t) c++;
      }
      c += __shfl_xor(c, 1, 64);
      c += __shfl_xor(c, 2, 64);
      c += __shfl_xor(c, 4, 64);
      c += __shfl_xor(c, 8, 64);
      if (l16 == 0) cnt2[w >> 1][rl] = c;       // each slot written exactly once
    }
  }
  __syncthreads();
  if (tid < 128) {
    int tot = cnt2[0][tid] + cnt2[1][tid];
    if (tot) atomicAdd(&out[m0 + tid], (float)tot);
  }
}

// ---- corrections: wave-cooperative dots over filter ∪ {true}, 8 waves ------
__global__ void corrections(const unsigned short* __restrict__ qb,
                            const unsigned short* __restrict__ rt,
                            const int* __restrict__ queries,
                            const int* __restrict__ filt,
                            const float* __restrict__ targets,
                            float* __restrict__ out) {
  int b = blockIdx.x;
  int tid = threadIdx.x;  // 512
  int w = tid >> 6, lane = tid & 63;
  __shared__ int idx[F_ + 1];
  __shared__ unsigned char uq[F_ + 1];
  if (tid <= F_) idx[tid] = (tid < F_) ? filt[b * F_ + tid] : queries[b * 3 + 2];
  __syncthreads();
  if (tid <= F_) {
    int p = idx[tid];
    bool u = true;
    for (int j = 0; j < tid; ++j)
      if (idx[j] == p) u = false;
    uq[tid] = u;
  }
  __syncthreads();
  float t = targets[b];
  float corr = 0.f;
  u16x8 qv = ((const u16x8*)(qb + (size_t)b * D_))[lane];
  for (int ii = w; ii <= F_; ii += 8) {
    if (!uq[ii]) continue;                       // wave-uniform branch
    int p = idx[ii];
    u16x8 rv = ((const u16x8*)(rt + (size_t)p * D_))[lane];
    float s = 0.f;
#pragma unroll
    for (int j = 0; j < 8; ++j) s += bf2f(qv[j]) * bf2f(rv[j]);
    for (int off = 32; off; off >>= 1) s += __shfl_down(s, off, 64);
    if (lane == 0)
      corr += (NEGV >= t ? 1.f : 0.f) - (s >= t ? 1.f : 0.f);
  }
  if (lane == 0 && corr != 0.f) atomicAdd(&out[b], corr);
}

// ---- fallback (ws too small): fp32 vector path, slow but correct -----------
__global__ void fallback_count(const float* __restrict__ q, const float* __restrict__ rhs,
                               const int* __restrict__ queries, const int* __restrict__ filt,
                               const float* __restrict__ targets, float* __restrict__ out) {
  int b = blockIdx.y;
  int n = blockIdx.x * 256 + threadIdx.x;
  __shared__ float qs[D_];
  __shared__ int idx[F_ + 1];
  __shared__ int cnt;
  for (int d = threadIdx.x; d < D_; d += 256) qs[d] = q[b * D_ + d];
  if (threadIdx.x < F_) idx[threadIdx.x] = filt[b * F_ + threadIdx.x];
  if (threadIdx.x == F_) idx[F_] = queries[b * 3 + 2];
  if (threadIdx.x == 0) cnt = 0;
  __syncthreads();
  if (n < N_) {
    float t = targets[b];
    float s = 0.f;
    for (int d = 0; d < D_; ++d) s += qs[d] * rhs[(size_t)d * N_ + n];
    bool member = false;
    for (int j = 0; j <= F_; ++j)
      if (idx[j] == n) member = true;
    float sv = member ? NEGV : s;
    if (sv >= t) atomicAdd(&cnt, 1);
  }
  __syncthreads();
  if (threadIdx.x == 0 && cnt) atomicAdd(&out[b], (float)cnt);
}

extern "C" void kernel_launch(void* const* d_in, const int* in_sizes, int n_in,
                              void* d_out, int out_size, void* d_ws, size_t ws_size,
                              hipStream_t stream) {
  const float* q = (const float*)d_in[0];
  const float* rhs = (const float*)d_in[1];
  const int* queries = (const int*)d_in[2];
  const int* filt = (const int*)d_in[3];
  float* out = (float*)d_out;

  char* wsb = (char*)d_ws;
  float* targets = (float*)wsb;                                   // 8 KB
  unsigned short* qb = (unsigned short*)(wsb + 8192);             // 2 MB
  unsigned short* rt = (unsigned short*)(wsb + 8192 + (size_t)B_ * D_ * 2);  // 102.4 MB
  size_t need = 8192 + (size_t)B_ * D_ * 2 + (size_t)N_ * D_ * 2;

  targets_init<<<B_, 256, 0, stream>>>(q, rhs, queries, targets, out);

  if (ws_size >= need) {
    convert_q<<<(B_ * D_ / 4) / 256, 256, 0, stream>>>(q, qb);
    transpose_rhs<<<dim3((N_ + 63) / 64, D_ / 64), 256, 0, stream>>>(rhs, rt);
    gemm_count<<<dim3(B_ / 128, (N_ + 127) / 128), 256, 0, stream>>>(qb, rt, targets, out);
    corrections<<<B_, 512, 0, stream>>>(qb, rt, queries, filt, targets, out);
  } else {
    fallback_count<<<dim3((N_ + 255) / 256, B_), 256, 0, stream>>>(q, rhs, queries, filt, targets, out);
  }
}

// Round 4
// 609.557 us; speedup vs baseline: 1.2083x; 1.2083x over previous
//
#include <hip/hip_runtime.h>
#include <hip/hip_bf16.h>

#define B_ 2048
#define D_ 512
#define N_ 100000
#define F_ 64
#define NEGV (-1000000.0f)

typedef __bf16 bfx8 __attribute__((ext_vector_type(8)));
typedef float f32x4 __attribute__((ext_vector_type(4)));
typedef unsigned short u16x8 __attribute__((ext_vector_type(8)));

static __device__ __forceinline__ unsigned short f2bf(float f) {
  unsigned u = __float_as_uint(f);
  unsigned r = (u + 0x7fffu + ((u >> 16) & 1u)) >> 16;
  return (unsigned short)r;
}
static __device__ __forceinline__ float bf2f(unsigned short u) {
  return __uint_as_float(((unsigned)u) << 16);
}

static __device__ __forceinline__ void async_copy16(const void* g, void* l) {
  __builtin_amdgcn_global_load_lds((const __attribute__((address_space(1))) void*)g,
                                   (__attribute__((address_space(3))) void*)l, 16, 0, 0);
}

// ---- targets (fp32, matches reference einsum) + out init + q->bf16 ---------
__global__ void targets_convert(const float* __restrict__ q, const float* __restrict__ rhs,
                                const int* __restrict__ queries, float* __restrict__ targets,
                                float* __restrict__ out, unsigned short* __restrict__ qb) {
  __shared__ float wsum[4];
  int b = blockIdx.x;
  int tid = threadIdx.x, lane = tid & 63, w = tid >> 6;
  int p = queries[b * 3 + 2];
  float2 v = ((const float2*)(q + (size_t)b * D_))[tid];   // 256 x 2 = 512 elems
  ushort2 o; o.x = f2bf(v.x); o.y = f2bf(v.y);
  ((ushort2*)(qb + (size_t)b * D_))[tid] = o;
  float s = v.x * rhs[(size_t)(2 * tid) * N_ + p] + v.y * rhs[(size_t)(2 * tid + 1) * N_ + p];
  for (int off = 32; off; off >>= 1) s += __shfl_down(s, off, 64);
  if (lane == 0) wsum[w] = s;
  __syncthreads();
  if (tid == 0) {
    targets[b] = wsum[0] + wsum[1] + wsum[2] + wsum[3];
    out[b] = 1.0f;
  }
}

// ---- rhs (D x N fp32) -> rt (N x D bf16), 64x64 LDS tile transpose ---------
__global__ void transpose_rhs(const float* __restrict__ rhs, unsigned short* __restrict__ rt) {
  __shared__ float tile[64][65];
  int n0 = blockIdx.x * 64, d0 = blockIdx.y * 64;
  int tid = threadIdx.x;
  if (n0 + 64 <= N_) {
#pragma unroll
    for (int p = 0; p < 4; ++p) {
      int e = p * 256 + tid;          // 1024 float4 chunks = 64 d x 16 n-chunks
      int d = e >> 4, c4 = e & 15;
      float4 v = *(const float4*)(rhs + (size_t)(d0 + d) * N_ + n0 + c4 * 4);
      tile[d][c4 * 4 + 0] = v.x; tile[d][c4 * 4 + 1] = v.y;
      tile[d][c4 * 4 + 2] = v.z; tile[d][c4 * 4 + 3] = v.w;
    }
  } else {
    int c = tid & 63, r4 = tid >> 6;
#pragma unroll
    for (int p = 0; p < 16; ++p) {
      int d = r4 + p * 4;
      if (n0 + c < N_) tile[d][c] = rhs[(size_t)(d0 + d) * N_ + n0 + c];
    }
  }
  __syncthreads();
#pragma unroll
  for (int p = 0; p < 4; ++p) {
    int e = p * 256 + tid;            // 1024 ushort4 slots = 64 n x 16 d-groups
    int n = e >> 4, dg = e & 15;
    if (n0 + n < N_) {
      ushort4 o;
      o.x = f2bf(tile[dg * 4 + 0][n]);
      o.y = f2bf(tile[dg * 4 + 1][n]);
      o.z = f2bf(tile[dg * 4 + 2][n]);
      o.w = f2bf(tile[dg * 4 + 3][n]);
      *(ushort4*)(rt + (size_t)(n0 + n) * D_ + d0 + dg * 4) = o;
    }
  }
}

// ---- main: bf16 MFMA GEMM, BK=32 double-buffered (1 barrier/kt) ------------
__global__ void __launch_bounds__(256) gemm_count(
    const unsigned short* __restrict__ qb,   // B x D bf16
    const unsigned short* __restrict__ rt,   // N x D bf16 (transposed rhs)
    const float* __restrict__ targets,
    float* __restrict__ out) {
  __shared__ unsigned short As[2][128 * 32];   // 2 x 8 KB
  __shared__ unsigned short Bs[2][128 * 32];
  __shared__ float sT[128];
  __shared__ int cnt2[2][128];

  int tid = threadIdx.x;
  int m0 = blockIdx.x * 128;
  int n0 = blockIdx.y * 128;

  if (tid < 128) sT[tid] = targets[m0 + tid];

  int w = tid >> 6, lane = tid & 63;
  int mw = (w & 1) * 64, nw = (w >> 1) * 64;
  int quad = lane >> 4, l16 = lane & 15;

  // per-thread staging coordinates (2 chunks of 16B per matrix per kt)
  int c0 = tid, c1 = 256 + tid;
  int am0 = c0 >> 2, aj0 = (c0 & 3) * 8;
  int am1 = c1 >> 2, aj1 = (c1 & 3) * 8;
  int bn0g = n0 + am0; if (bn0g > N_ - 1) bn0g = N_ - 1;
  int bn1g = n0 + am1; if (bn1g > N_ - 1) bn1g = N_ - 1;
  const unsigned short* agp0 = qb + (size_t)(m0 + am0) * D_ + aj0;
  const unsigned short* agp1 = qb + (size_t)(m0 + am1) * D_ + aj1;
  const unsigned short* bgp0 = rt + (size_t)bn0g * D_ + aj0;
  const unsigned short* bgp1 = rt + (size_t)bn1g * D_ + aj1;

  f32x4 acc[4][4];
  f32x4 z = {0.f, 0.f, 0.f, 0.f};
#pragma unroll
  for (int i = 0; i < 4; ++i)
#pragma unroll
    for (int j = 0; j < 4; ++j) acc[i][j] = z;

  // prologue: stage kt=0 into buffer 0
  async_copy16(agp0, &As[0][c0 * 8]);
  async_copy16(agp1, &As[0][c1 * 8]);
  async_copy16(bgp0, &Bs[0][c0 * 8]);
  async_copy16(bgp1, &Bs[0][c1 * 8]);

  for (int kt = 0; kt < 16; ++kt) {
    int buf = kt & 1;
    __syncthreads();                    // drains kt's copies; frees other buffer
    if (kt + 1 < 16) {
      int nb = 1 - buf, k1 = (kt + 1) * 32;
      async_copy16(agp0 + k1, &As[nb][c0 * 8]);
      async_copy16(agp1 + k1, &As[nb][c1 * 8]);
      async_copy16(bgp0 + k1, &Bs[nb][c0 * 8]);
      async_copy16(bgp1 + k1, &Bs[nb][c1 * 8]);
    }

    bfx8 a[4], b[4];
#pragma unroll
    for (int mi = 0; mi < 4; ++mi) {
      int m = mw + mi * 16 + l16;
      u16x8 au = *(const u16x8*)(&As[buf][m * 32 + quad * 8]);
      a[mi] = __builtin_bit_cast(bfx8, au);
    }
#pragma unroll
    for (int ni = 0; ni < 4; ++ni) {
      int n = nw + ni * 16 + l16;
      u16x8 bu = *(const u16x8*)(&Bs[buf][n * 32 + quad * 8]);
      b[ni] = __builtin_bit_cast(bfx8, bu);
    }
#pragma unroll
    for (int mi = 0; mi < 4; ++mi)
#pragma unroll
      for (int ni = 0; ni < 4; ++ni)
        acc[mi][ni] = __builtin_amdgcn_mfma_f32_16x16x32_bf16(a[mi], b[ni], acc[mi][ni], 0, 0, 0);
  }

  // epilogue: compare vs target, quad shuffle-reduce, conflict-free stores
#pragma unroll
  for (int mi = 0; mi < 4; ++mi) {
#pragma unroll
    for (int reg = 0; reg < 4; ++reg) {
      int rl = mw + mi * 16 + quad * 4 + reg;   // C/D: row=(lane>>4)*4+reg
      float t = sT[rl];
      int c = 0;
#pragma unroll
      for (int ni = 0; ni < 4; ++ni) {
        int col = n0 + nw + ni * 16 + l16;      // C/D: col=lane&15
        if (col < N_ && acc[mi][ni][reg] >= t) c++;
      }
      c += __shfl_xor(c, 1, 64);
      c += __shfl_xor(c, 2, 64);
      c += __shfl_xor(c, 4, 64);
      c += __shfl_xor(c, 8, 64);
      if (l16 == 0) cnt2[w >> 1][rl] = c;       // each slot written exactly once
    }
  }
  __syncthreads();
  if (tid < 128) {
    int tot = cnt2[0][tid] + cnt2[1][tid];
    if (tot) atomicAdd(&out[m0 + tid], (float)tot);
  }
}

// ---- corrections: wave-cooperative dots over filter ∪ {true}, 8 waves ------
__global__ void corrections(const unsigned short* __restrict__ qb,
                            const unsigned short* __restrict__ rt,
                            const int* __restrict__ queries,
                            const int* __restrict__ filt,
                            const float* __restrict__ targets,
                            float* __restrict__ out) {
  int b = blockIdx.x;
  int tid = threadIdx.x;  // 512
  int w = tid >> 6, lane = tid & 63;
  __shared__ int idx[F_ + 1];
  __shared__ unsigned char uq[F_ + 1];
  if (tid <= F_) idx[tid] = (tid < F_) ? filt[b * F_ + tid] : queries[b * 3 + 2];
  __syncthreads();
  if (tid <= F_) {
    int p = idx[tid];
    bool u = true;
    for (int j = 0; j < tid; ++j)
      if (idx[j] == p) u = false;
    uq[tid] = u;
  }
  __syncthreads();
  float t = targets[b];
  float corr = 0.f;
  u16x8 qv = ((const u16x8*)(qb + (size_t)b * D_))[lane];
  for (int ii = w; ii <= F_; ii += 8) {
    if (!uq[ii]) continue;                       // wave-uniform branch
    int p = idx[ii];
    u16x8 rv = ((const u16x8*)(rt + (size_t)p * D_))[lane];
    float s = 0.f;
#pragma unroll
    for (int j = 0; j < 8; ++j) s += bf2f(qv[j]) * bf2f(rv[j]);
    for (int off = 32; off; off >>= 1) s += __shfl_down(s, off, 64);
    if (lane == 0)
      corr += (NEGV >= t ? 1.f : 0.f) - (s >= t ? 1.f : 0.f);
  }
  if (lane == 0 && corr != 0.f) atomicAdd(&out[b], corr);
}

// ---- fallback path (ws too small) ------------------------------------------
__global__ void targets_init(const float* __restrict__ q, const float* __restrict__ rhs,
                             const int* __restrict__ queries, float* __restrict__ targets,
                             float* __restrict__ out) {
  __shared__ float wsum[4];
  int b = blockIdx.x;
  int tid = threadIdx.x, lane = tid & 63, w = tid >> 6;
  int p = queries[b * 3 + 2];
  float s = 0.f;
  for (int d = tid; d < D_; d += 256) s += q[b * D_ + d] * rhs[(size_t)d * N_ + p];
  for (int off = 32; off; off >>= 1) s += __shfl_down(s, off, 64);
  if (lane == 0) wsum[w] = s;
  __syncthreads();
  if (tid == 0) {
    targets[b] = wsum[0] + wsum[1] + wsum[2] + wsum[3];
    out[b] = 1.0f;
  }
}

__global__ void fallback_count(const float* __restrict__ q, const float* __restrict__ rhs,
                               const int* __restrict__ queries, const int* __restrict__ filt,
                               const float* __restrict__ targets, float* __restrict__ out) {
  int b = blockIdx.y;
  int n = blockIdx.x * 256 + threadIdx.x;
  __shared__ float qs[D_];
  __shared__ int idx[F_ + 1];
  __shared__ int cnt;
  for (int d = threadIdx.x; d < D_; d += 256) qs[d] = q[b * D_ + d];
  if (threadIdx.x < F_) idx[threadIdx.x] = filt[b * F_ + threadIdx.x];
  if (threadIdx.x == F_) idx[F_] = queries[b * 3 + 2];
  if (threadIdx.x == 0) cnt = 0;
  __syncthreads();
  if (n < N_) {
    float t = targets[b];
    float s = 0.f;
    for (int d = 0; d < D_; ++d) s += qs[d] * rhs[(size_t)d * N_ + n];
    bool member = false;
    for (int j = 0; j <= F_; ++j)
      if (idx[j] == n) member = true;
    float sv = member ? NEGV : s;
    if (sv >= t) atomicAdd(&cnt, 1);
  }
  __syncthreads();
  if (threadIdx.x == 0 && cnt) atomicAdd(&out[b], (float)cnt);
}

extern "C" void kernel_launch(void* const* d_in, const int* in_sizes, int n_in,
                              void* d_out, int out_size, void* d_ws, size_t ws_size,
                              hipStream_t stream) {
  const float* q = (const float*)d_in[0];
  const float* rhs = (const float*)d_in[1];
  const int* queries = (const int*)d_in[2];
  const int* filt = (const int*)d_in[3];
  float* out = (float*)d_out;

  char* wsb = (char*)d_ws;
  float* targets = (float*)wsb;                                   // 8 KB
  unsigned short* qb = (unsigned short*)(wsb + 8192);             // 2 MB
  unsigned short* rt = (unsigned short*)(wsb + 8192 + (size_t)B_ * D_ * 2);  // 102.4 MB
  size_t need = 8192 + (size_t)B_ * D_ * 2 + (size_t)N_ * D_ * 2;

  if (ws_size >= need) {
    targets_convert<<<B_, 256, 0, stream>>>(q, rhs, queries, targets, out, qb);
    transpose_rhs<<<dim3((N_ + 63) / 64, D_ / 64), 256, 0, stream>>>(rhs, rt);
    gemm_count<<<dim3(B_ / 128, (N_ + 127) / 128), 256, 0, stream>>>(qb, rt, targets, out);
    corrections<<<B_, 512, 0, stream>>>(qb, rt, queries, filt, targets, out);
  } else {
    targets_init<<<B_, 256, 0, stream>>>(q, rhs, queries, targets, out);
    fallback_count<<<dim3((N_ + 255) / 256, B_), 256, 0, stream>>>(q, rhs, queries, filt, targets, out);
  }
}